// Round 15
// baseline (161.145 us; speedup 1.0000x reference)
//
#include <hip/hip_runtime.h>
#include <math.h>

#define TWO_PI 6.28318530717958647692f

typedef float f4 __attribute__((ext_vector_type(4)));

// ---------------------------------------------------------------------------
// K1: cartesian -> polar sampling.  pf[b][c][a][r], one thread per element.
// (r11-exact, measured-best form.)
// ---------------------------------------------------------------------------
__global__ __launch_bounds__(256) void k1_cart2polar(const float* __restrict__ x,
                                                     float* __restrict__ pf) {
    __shared__ float w00s[128], w01s[128], w10s[128], w11s[128];
    __shared__ int   o00s[128], o01s[128], o10s[128], o11s[128];
    int tid = threadIdx.x;
    if (tid < 128) {
        int a = tid >> 3, r = tid & 7;
        float theta = (TWO_PI * (float)a) / 16.0f;
        float rad   = ((float)r + 0.5f) / 8.0f * 64.0f;
        float ys = 63.5f + rad * sinf(theta);
        float xs = 63.5f + rad * cosf(theta);
        float y0 = floorf(ys), x0 = floorf(xs);
        float wy = ys - y0,    wx = xs - x0;
        int y0i = min(max((int)y0, 0), 127);
        int y1i = min(max((int)y0 + 1, 0), 127);
        int x0i = min(max((int)x0, 0), 127);
        int x1i = min(max((int)x0 + 1, 0), 127);
        float valid = (ys >= 0.0f && ys <= 127.0f && xs >= 0.0f && xs <= 127.0f) ? 1.0f : 0.0f;
        w00s[tid] = valid * (1.0f - wy) * (1.0f - wx);
        w01s[tid] = valid * (1.0f - wy) * wx;
        w10s[tid] = valid * wy * (1.0f - wx);
        w11s[tid] = valid * wy * wx;
        o00s[tid] = y0i * 128 + x0i;
        o01s[tid] = y0i * 128 + x1i;
        o10s[tid] = y1i * 128 + x0i;
        o11s[tid] = y1i * 128 + x1i;
    }
    __syncthreads();
    int t = blockIdx.x * 256 + tid;     // < 524288
    int bin = t & 127;
    int img = t >> 7;                   // b*256 + c
    const float* ib = x + ((size_t)img << 14);
    float v = ib[o00s[bin]] * w00s[bin]
            + ib[o01s[bin]] * w01s[bin]
            + ib[o10s[bin]] * w10s[bin]
            + ib[o11s[bin]] * w11s[bin];
    pf[t] = v;
}

// ---------------------------------------------------------------------------
// K2: grouped 3x3 conv over (A=16,R=8), zero-pad 1, groups=4.
// r14 base (512 blocks = b,g,ot; 2 passes of 32 ic; identical staging totals)
// with ONE change: 256 threads (thread = 1 bin x 4 oc) instead of 128
// (bin-pair x 4 oc).  Halves per-thread work, doubles waves/CU (4 -> 8) so
// staging latency and pass barriers overlap across more waves.
// Output: pp_t[b][bin][oc].
// ---------------------------------------------------------------------------
__global__ __launch_bounds__(256) void k2_conv(const float* __restrict__ pf,
                                               const float* __restrict__ w_polar,
                                               const float* __restrict__ b_polar,
                                               float* __restrict__ pp_t) {
    __shared__ __align__(16) float pfs[32 * 180];   // [icl][a+halo][r+halo]
    __shared__ __align__(16) float wls[32 * 72];    // [icl][tap][j]  j=0..7
    int bid = blockIdx.x;               // 512
    int b  = bid >> 5;
    int g  = (bid >> 3) & 3;
    int ot = bid & 7;
    int tid = threadIdx.x;              // 0..255
    int bin = tid >> 1;                 // 0..127
    int ocq = tid & 1;                  // 0..1   oc-quad within the 8-oc slot
    int a = bin >> 3, r = bin & 7;
    int oc0 = g * 64 + ot * 8;

    for (int i = tid; i < 32 * 180; i += 256) pfs[i] = 0.0f;   // halo stays 0
    __syncthreads();

    f4 acc = {};
    const float* src = pf + ((size_t)(b * 256 + g * 64) << 7);

    for (int pass = 0; pass < 2; ++pass) {
        // stage pf sub-tile (interior only; halo cells remain zero)
        for (int i = tid; i < 4096; i += 256) {
            int icl = i >> 7, bn = i & 127;
            pfs[icl * 180 + ((bn >> 3) + 1) * 10 + (bn & 7) + 1]
                = src[pass * 4096 + i];
        }
        // stage weights transposed: wls[icl*72 + tap*8 + j]
        for (int i = tid; i < 2304; i += 256) {
            int icl = i / 72, rem = i - icl * 72;
            int tap = rem >> 3, j = rem & 7;
            wls[i] = w_polar[(size_t)(oc0 + j) * 576 + (pass * 32 + icl) * 9 + tap];
        }
        __syncthreads();

        const float* pbase = pfs + a * 10 + r;
        const float* wbase = wls + ocq * 4;
        for (int ic = 0; ic < 32; ++ic) {
            float v[9];
            const float* base = pbase + ic * 180;
            #pragma unroll
            for (int dh = 0; dh < 3; ++dh)
                #pragma unroll
                for (int dw = 0; dw < 3; ++dw)
                    v[dh * 3 + dw] = base[dh * 10 + dw];
            const float* wr = wbase + ic * 72;
            #pragma unroll
            for (int tap = 0; tap < 9; ++tap) {
                f4 wv = *(const f4*)(wr + tap * 8);
                acc += wv * v[tap];
            }
        }
        __syncthreads();    // before restaging
    }

    f4 bias = *(const f4*)(b_polar + oc0 + ocq * 4);
    *(f4*)(pp_t + ((size_t)(b * 128 + bin)) * 256 + oc0 + ocq * 4) = acc + bias;
}

// ---------------------------------------------------------------------------
// K3: q[b][bin][o] = sum_c w_attn1[o][c] * pp_t[b][bin][c]   (r11-exact)
// ---------------------------------------------------------------------------
__global__ __launch_bounds__(256) void k3_proj(const float* __restrict__ pp_t,
                                               const float* __restrict__ w_attn1,
                                               float* __restrict__ q) {
    __shared__ __align__(16) float wl[16384];
    int tid = threadIdx.x;
    for (int i = tid; i < 16384; i += 256) {       // i = o*256 + c
        int o = i >> 8, c = i & 255;
        wl[(c << 6) + (o ^ (c & 31))] = w_attn1[i];
    }
    __syncthreads();
    int n = blockIdx.x * 256 + tid;     // < 131072
    int b   = n >> 13;
    int bin = (n >> 6) & 127;
    int o   = n & 63;
    const float4* pr4 = (const float4*)(pp_t + ((size_t)((b << 7) + bin)) * 256);
    float acc = 0.0f;
    #pragma unroll 8
    for (int c4 = 0; c4 < 64; ++c4) {
        float4 p = pr4[c4];
        int c = c4 << 2;
        acc += wl[( c      << 6) + (o ^ ( c      & 31))] * p.x;
        acc += wl[((c + 1) << 6) + (o ^ ((c + 1) & 31))] * p.y;
        acc += wl[((c + 2) << 6) + (o ^ ((c + 2) & 31))] * p.z;
        acc += wl[((c + 3) << 6) + (o ^ ((c + 3) & 31))] * p.w;
    }
    q[n] = acc;
}

// ---------------------------------------------------------------------------
// K4a: attention map att[b][h][w]. 1024 blocks, 1 px/thread.  (r11-exact)
// ---------------------------------------------------------------------------
__global__ __launch_bounds__(256) void k4a_att(const float* __restrict__ q,
                                               const float* __restrict__ b_attn1,
                                               const float* __restrict__ w_attn2,
                                               const float* __restrict__ b_attn2,
                                               float* __restrict__ att) {
    __shared__ __align__(16) float qs[8896];
    __shared__ __align__(16) float b1s[64];
    __shared__ __align__(16) float w2s[64];
    int b    = blockIdx.x >> 6;
    int tile = blockIdx.x & 63;
    int tid  = threadIdx.x;
    const float* qb = q + ((size_t)b << 13);
    for (int i = tid; i < 8192; i += 256) {
        int bin = i >> 6, o = i & 63;
        qs[(bin >> 3) * 556 + (bin & 7) * 68 + o] = qb[i];
    }
    if (tid < 64) { b1s[tid] = b_attn1[tid]; w2s[tid] = w_attn2[tid]; }
    __syncthreads();
    float b2 = b_attn2[0];
    const float4* q4  = (const float4*)qs;
    const float4* b14 = (const float4*)b1s;
    const float4* w24 = (const float4*)w2s;

    int p = (tile << 8) + tid;
    int h = p >> 7, w = p & 127;
    float dy = (float)h - 63.5f;
    float dx = (float)w - 63.5f;
    float rr = sqrtf(dy * dy + dx * dx);
    float th = atan2f(dy, dx);
    if (th < 0.0f) th += TWO_PI;
    float aa = th / TWO_PI * 16.0f;
    float a0 = floorf(aa);
    float wa = aa - a0;
    int ia0 = ((int)a0) & 15;
    int ia1 = (ia0 + 1) & 15;
    float ri = rr / 64.0f * 8.0f - 0.5f;
    float r0 = floorf(ri);
    float wr = ri - r0;
    int ir0 = (int)fminf(fmaxf(r0, 0.0f), 7.0f);
    int ir1 = (int)fminf(fmaxf(r0 + 1.0f, 0.0f), 7.0f);
    float valid = (rr <= 64.0f) ? 1.0f : 0.0f;
    float w00 = valid * (1.0f - wa) * (1.0f - wr);
    float w01 = valid * (1.0f - wa) * wr;
    float w10 = valid * wa * (1.0f - wr);
    float w11 = valid * wa * wr;
    int t00 = ia0 * 139 + ir0 * 17;
    int t01 = ia0 * 139 + ir1 * 17;
    int t10 = ia1 * 139 + ir0 * 17;
    int t11 = ia1 * 139 + ir1 * 17;
    float acc = b2;
    #pragma unroll
    for (int i = 0; i < 16; ++i) {
        float4 v00 = q4[t00 + i], v01 = q4[t01 + i];
        float4 v10 = q4[t10 + i], v11 = q4[t11 + i];
        float4 bb = b14[i], ww = w24[i];
        float sx = w00 * v00.x + w01 * v01.x + w10 * v10.x + w11 * v11.x;
        float sy = w00 * v00.y + w01 * v01.y + w10 * v10.y + w11 * v11.y;
        float sz = w00 * v00.z + w01 * v01.z + w10 * v10.z + w11 * v11.z;
        float sw = w00 * v00.w + w01 * v01.w + w10 * v10.w + w11 * v11.w;
        acc += fmaxf(sx + bb.x, 0.0f) * ww.x;
        acc += fmaxf(sy + bb.y, 0.0f) * ww.y;
        acc += fmaxf(sz + bb.z, 0.0f) * ww.z;
        acc += fmaxf(sw + bb.w, 0.0f) * ww.w;
    }
    float attv = 1.0f / (1.0f + __expf(-acc));
    att[((size_t)b << 14) + p] = attv;
}

// ---------------------------------------------------------------------------
// K4b: out = x * att. r11-exact: grid-stride, NT load/store, 2048 blocks.
// ---------------------------------------------------------------------------
__global__ __launch_bounds__(256) void k4b_mul(const f4* __restrict__ x4,
                                               const float* __restrict__ att,
                                               f4* __restrict__ out4) {
    const f4* att4 = (const f4*)att;
    int idx = blockIdx.x * 256 + threadIdx.x;
    int stride = gridDim.x * 256;
    for (int i = idx; i < 16777216; i += stride) {
        f4 xv = __builtin_nontemporal_load(&x4[i]);
        f4 av = att4[((i >> 20) << 12) | (i & 4095)];
        __builtin_nontemporal_store(xv * av, &out4[i]);
    }
}

// ---------------------------------------------------------------------------
extern "C" void kernel_launch(void* const* d_in, const int* in_sizes, int n_in,
                              void* d_out, int out_size, void* d_ws, size_t ws_size,
                              hipStream_t stream) {
    const float* x       = (const float*)d_in[0];
    const float* w_polar = (const float*)d_in[1];
    const float* b_polar = (const float*)d_in[2];
    const float* w_attn1 = (const float*)d_in[3];
    const float* b_attn1 = (const float*)d_in[4];
    const float* w_attn2 = (const float*)d_in[5];
    const float* b_attn2 = (const float*)d_in[6];
    float* out = (float*)d_out;
    float* ws  = (float*)d_ws;

    float* pf   = ws;                 // 524288 f  [b][c][a][r]
    float* pp_t = ws + 524288;        // 524288 f  [b][bin][c]
    float* q    = ws + 1048576;       // 131072 f  [b][bin][o]
    float* att  = ws + 1179648;       // 262144 f  [b][h][w]

    hipLaunchKernelGGL(k1_cart2polar, dim3(2048), dim3(256), 0, stream, x, pf);
    hipLaunchKernelGGL(k2_conv,       dim3(512),  dim3(256), 0, stream,
                       pf, w_polar, b_polar, pp_t);
    hipLaunchKernelGGL(k3_proj,       dim3(512),  dim3(256), 0, stream, pp_t, w_attn1, q);
    hipLaunchKernelGGL(k4a_att,       dim3(1024), dim3(256), 0, stream,
                       q, b_attn1, w_attn2, b_attn2, att);
    hipLaunchKernelGGL(k4b_mul,       dim3(2048), dim3(256), 0, stream,
                       (const f4*)x, att, (f4*)out);
}

// Round 16
// 157.232 us; speedup vs baseline: 1.0249x; 1.0249x over previous
//
#include <hip/hip_runtime.h>
#include <math.h>

#define TWO_PI 6.28318530717958647692f

typedef float f4 __attribute__((ext_vector_type(4)));

// ---------------------------------------------------------------------------
// K1: cartesian -> polar sampling.  pf[b][c][a][r], one thread per element.
// (r11-exact, measured-best form.)
// ---------------------------------------------------------------------------
__global__ __launch_bounds__(256) void k1_cart2polar(const float* __restrict__ x,
                                                     float* __restrict__ pf) {
    __shared__ float w00s[128], w01s[128], w10s[128], w11s[128];
    __shared__ int   o00s[128], o01s[128], o10s[128], o11s[128];
    int tid = threadIdx.x;
    if (tid < 128) {
        int a = tid >> 3, r = tid & 7;
        float theta = (TWO_PI * (float)a) / 16.0f;
        float rad   = ((float)r + 0.5f) / 8.0f * 64.0f;
        float ys = 63.5f + rad * sinf(theta);
        float xs = 63.5f + rad * cosf(theta);
        float y0 = floorf(ys), x0 = floorf(xs);
        float wy = ys - y0,    wx = xs - x0;
        int y0i = min(max((int)y0, 0), 127);
        int y1i = min(max((int)y0 + 1, 0), 127);
        int x0i = min(max((int)x0, 0), 127);
        int x1i = min(max((int)x0 + 1, 0), 127);
        float valid = (ys >= 0.0f && ys <= 127.0f && xs >= 0.0f && xs <= 127.0f) ? 1.0f : 0.0f;
        w00s[tid] = valid * (1.0f - wy) * (1.0f - wx);
        w01s[tid] = valid * (1.0f - wy) * wx;
        w10s[tid] = valid * wy * (1.0f - wx);
        w11s[tid] = valid * wy * wx;
        o00s[tid] = y0i * 128 + x0i;
        o01s[tid] = y0i * 128 + x1i;
        o10s[tid] = y1i * 128 + x0i;
        o11s[tid] = y1i * 128 + x1i;
    }
    __syncthreads();
    int t = blockIdx.x * 256 + tid;     // < 524288
    int bin = t & 127;
    int img = t >> 7;                   // b*256 + c
    const float* ib = x + ((size_t)img << 14);
    float v = ib[o00s[bin]] * w00s[bin]
            + ib[o01s[bin]] * w01s[bin]
            + ib[o10s[bin]] * w10s[bin]
            + ib[o11s[bin]] * w11s[bin];
    pf[t] = v;
}

// ---------------------------------------------------------------------------
// K2: grouped 3x3 conv over (A=16,R=8), zero-pad 1, groups=4.
// (r14-exact, measured-best: 512 blocks, 256 threads = 1 bin x 4 oc,
//  2 passes of 32 ic, LDS-staged weights.)  Output: pp_t[b][bin][oc].
// ---------------------------------------------------------------------------
__global__ __launch_bounds__(256) void k2_conv(const float* __restrict__ pf,
                                               const float* __restrict__ w_polar,
                                               const float* __restrict__ b_polar,
                                               float* __restrict__ pp_t) {
    __shared__ __align__(16) float pfs[32 * 180];   // [icl][a+halo][r+halo]
    __shared__ __align__(16) float wls[32 * 72];    // [icl][tap][j]  j=0..7
    int bid = blockIdx.x;               // 512
    int b  = bid >> 5;
    int g  = (bid >> 3) & 3;
    int ot = bid & 7;
    int tid = threadIdx.x;              // 0..255
    int bin = tid >> 1;                 // 0..127
    int ocq = tid & 1;                  // 0..1   oc-quad within the 8-oc slot
    int a = bin >> 3, r = bin & 7;
    int oc0 = g * 64 + ot * 8;

    for (int i = tid; i < 32 * 180; i += 256) pfs[i] = 0.0f;   // halo stays 0
    __syncthreads();

    f4 acc = {};
    const float* src = pf + ((size_t)(b * 256 + g * 64) << 7);

    for (int pass = 0; pass < 2; ++pass) {
        for (int i = tid; i < 4096; i += 256) {
            int icl = i >> 7, bn = i & 127;
            pfs[icl * 180 + ((bn >> 3) + 1) * 10 + (bn & 7) + 1]
                = src[pass * 4096 + i];
        }
        for (int i = tid; i < 2304; i += 256) {
            int icl = i / 72, rem = i - icl * 72;
            int tap = rem >> 3, j = rem & 7;
            wls[i] = w_polar[(size_t)(oc0 + j) * 576 + (pass * 32 + icl) * 9 + tap];
        }
        __syncthreads();

        const float* pbase = pfs + a * 10 + r;
        const float* wbase = wls + ocq * 4;
        for (int ic = 0; ic < 32; ++ic) {
            float v[9];
            const float* base = pbase + ic * 180;
            #pragma unroll
            for (int dh = 0; dh < 3; ++dh)
                #pragma unroll
                for (int dw = 0; dw < 3; ++dw)
                    v[dh * 3 + dw] = base[dh * 10 + dw];
            const float* wr = wbase + ic * 72;
            #pragma unroll
            for (int tap = 0; tap < 9; ++tap) {
                f4 wv = *(const f4*)(wr + tap * 8);
                acc += wv * v[tap];
            }
        }
        __syncthreads();    // before restaging
    }

    f4 bias = *(const f4*)(b_polar + oc0 + ocq * 4);
    *(f4*)(pp_t + ((size_t)(b * 128 + bin)) * 256 + oc0 + ocq * 4) = acc + bias;
}

// ---------------------------------------------------------------------------
// K3: q[b][bin][o] = sum_c w_attn1[o][c] * pp_t[b][bin][c]   (r11-exact)
// ---------------------------------------------------------------------------
__global__ __launch_bounds__(256) void k3_proj(const float* __restrict__ pp_t,
                                               const float* __restrict__ w_attn1,
                                               float* __restrict__ q) {
    __shared__ __align__(16) float wl[16384];
    int tid = threadIdx.x;
    for (int i = tid; i < 16384; i += 256) {       // i = o*256 + c
        int o = i >> 8, c = i & 255;
        wl[(c << 6) + (o ^ (c & 31))] = w_attn1[i];
    }
    __syncthreads();
    int n = blockIdx.x * 256 + tid;     // < 131072
    int b   = n >> 13;
    int bin = (n >> 6) & 127;
    int o   = n & 63;
    const float4* pr4 = (const float4*)(pp_t + ((size_t)((b << 7) + bin)) * 256);
    float acc = 0.0f;
    #pragma unroll 8
    for (int c4 = 0; c4 < 64; ++c4) {
        float4 p = pr4[c4];
        int c = c4 << 2;
        acc += wl[( c      << 6) + (o ^ ( c      & 31))] * p.x;
        acc += wl[((c + 1) << 6) + (o ^ ((c + 1) & 31))] * p.y;
        acc += wl[((c + 2) << 6) + (o ^ ((c + 2) & 31))] * p.z;
        acc += wl[((c + 3) << 6) + (o ^ ((c + 3) & 31))] * p.w;
    }
    q[n] = acc;
}

// ---------------------------------------------------------------------------
// K4a: attention map att[b][h][w]. 1024 blocks, 1 px/thread.  (r11-exact)
// ---------------------------------------------------------------------------
__global__ __launch_bounds__(256) void k4a_att(const float* __restrict__ q,
                                               const float* __restrict__ b_attn1,
                                               const float* __restrict__ w_attn2,
                                               const float* __restrict__ b_attn2,
                                               float* __restrict__ att) {
    __shared__ __align__(16) float qs[8896];
    __shared__ __align__(16) float b1s[64];
    __shared__ __align__(16) float w2s[64];
    int b    = blockIdx.x >> 6;
    int tile = blockIdx.x & 63;
    int tid  = threadIdx.x;
    const float* qb = q + ((size_t)b << 13);
    for (int i = tid; i < 8192; i += 256) {
        int bin = i >> 6, o = i & 63;
        qs[(bin >> 3) * 556 + (bin & 7) * 68 + o] = qb[i];
    }
    if (tid < 64) { b1s[tid] = b_attn1[tid]; w2s[tid] = w_attn2[tid]; }
    __syncthreads();
    float b2 = b_attn2[0];
    const float4* q4  = (const float4*)qs;
    const float4* b14 = (const float4*)b1s;
    const float4* w24 = (const float4*)w2s;

    int p = (tile << 8) + tid;
    int h = p >> 7, w = p & 127;
    float dy = (float)h - 63.5f;
    float dx = (float)w - 63.5f;
    float rr = sqrtf(dy * dy + dx * dx);
    float th = atan2f(dy, dx);
    if (th < 0.0f) th += TWO_PI;
    float aa = th / TWO_PI * 16.0f;
    float a0 = floorf(aa);
    float wa = aa - a0;
    int ia0 = ((int)a0) & 15;
    int ia1 = (ia0 + 1) & 15;
    float ri = rr / 64.0f * 8.0f - 0.5f;
    float r0 = floorf(ri);
    float wr = ri - r0;
    int ir0 = (int)fminf(fmaxf(r0, 0.0f), 7.0f);
    int ir1 = (int)fminf(fmaxf(r0 + 1.0f, 0.0f), 7.0f);
    float valid = (rr <= 64.0f) ? 1.0f : 0.0f;
    float w00 = valid * (1.0f - wa) * (1.0f - wr);
    float w01 = valid * (1.0f - wa) * wr;
    float w10 = valid * wa * (1.0f - wr);
    float w11 = valid * wa * wr;
    int t00 = ia0 * 139 + ir0 * 17;
    int t01 = ia0 * 139 + ir1 * 17;
    int t10 = ia1 * 139 + ir0 * 17;
    int t11 = ia1 * 139 + ir1 * 17;
    float acc = b2;
    #pragma unroll
    for (int i = 0; i < 16; ++i) {
        float4 v00 = q4[t00 + i], v01 = q4[t01 + i];
        float4 v10 = q4[t10 + i], v11 = q4[t11 + i];
        float4 bb = b14[i], ww = w24[i];
        float sx = w00 * v00.x + w01 * v01.x + w10 * v10.x + w11 * v11.x;
        float sy = w00 * v00.y + w01 * v01.y + w10 * v10.y + w11 * v11.y;
        float sz = w00 * v00.z + w01 * v01.z + w10 * v10.z + w11 * v11.z;
        float sw = w00 * v00.w + w01 * v01.w + w10 * v10.w + w11 * v11.w;
        acc += fmaxf(sx + bb.x, 0.0f) * ww.x;
        acc += fmaxf(sy + bb.y, 0.0f) * ww.y;
        acc += fmaxf(sz + bb.z, 0.0f) * ww.z;
        acc += fmaxf(sw + bb.w, 0.0f) * ww.w;
    }
    float attv = 1.0f / (1.0f + __expf(-acc));
    att[((size_t)b << 14) + p] = attv;
}

// ---------------------------------------------------------------------------
// K4b: out = x * att.  NEW: block = one contiguous 8192-float4 chunk
// (= 2 channels of one batch); its att slice (4096 f4 = 64 KB) staged in LDS
// once, coalesced.  Hot loop: zero L2 side-traffic, no addr shift/mask.
// 2048 blocks x 256 threads, NT on both HBM streams.
// ---------------------------------------------------------------------------
__global__ __launch_bounds__(256) void k4b_mul(const f4* __restrict__ x4,
                                               const float* __restrict__ att,
                                               f4* __restrict__ out4) {
    __shared__ __align__(16) f4 attl[4096];     // 64 KB
    int tid = threadIdx.x;
    size_t chunk = (size_t)blockIdx.x * 8192;   // covers 2048*8192 = 16.7M f4
    const f4* atts = (const f4*)att + ((chunk >> 20) << 12);  // batch slice
    #pragma unroll
    for (int k = 0; k < 16; ++k)
        attl[k * 256 + tid] = atts[k * 256 + tid];
    __syncthreads();
    #pragma unroll 2
    for (int k = 0; k < 32; ++k) {
        size_t i = chunk + k * 256 + tid;
        f4 xv = __builtin_nontemporal_load(&x4[i]);
        f4 av = attl[(k * 256 + tid) & 4095];
        __builtin_nontemporal_store(xv * av, &out4[i]);
    }
}

// ---------------------------------------------------------------------------
extern "C" void kernel_launch(void* const* d_in, const int* in_sizes, int n_in,
                              void* d_out, int out_size, void* d_ws, size_t ws_size,
                              hipStream_t stream) {
    const float* x       = (const float*)d_in[0];
    const float* w_polar = (const float*)d_in[1];
    const float* b_polar = (const float*)d_in[2];
    const float* w_attn1 = (const float*)d_in[3];
    const float* b_attn1 = (const float*)d_in[4];
    const float* w_attn2 = (const float*)d_in[5];
    const float* b_attn2 = (const float*)d_in[6];
    float* out = (float*)d_out;
    float* ws  = (float*)d_ws;

    float* pf   = ws;                 // 524288 f  [b][c][a][r]
    float* pp_t = ws + 524288;        // 524288 f  [b][bin][c]
    float* q    = ws + 1048576;       // 131072 f  [b][bin][o]
    float* att  = ws + 1179648;       // 262144 f  [b][h][w]

    hipLaunchKernelGGL(k1_cart2polar, dim3(2048), dim3(256), 0, stream, x, pf);
    hipLaunchKernelGGL(k2_conv,       dim3(512),  dim3(256), 0, stream,
                       pf, w_polar, b_polar, pp_t);
    hipLaunchKernelGGL(k3_proj,       dim3(512),  dim3(256), 0, stream, pp_t, w_attn1, q);
    hipLaunchKernelGGL(k4a_att,       dim3(1024), dim3(256), 0, stream,
                       q, b_attn1, w_attn2, b_attn2, att);
    hipLaunchKernelGGL(k4b_mul,       dim3(2048), dim3(256), 0, stream,
                       (const f4*)x, att, (f4*)out);
}